// Round 3
// baseline (1035.166 us; speedup 1.0000x reference)
//
#include <hip/hip_runtime.h>

#define SEQ   512
#define BATCH 64
#define HID   1024
#define NX    8

// ---------------------------------------------------------------------------
// WVT[h][n] = WV[n][h]  (one-time 32x32 tiled transpose)
// ---------------------------------------------------------------------------
__global__ __launch_bounds__(256) void transpose_k(
    const float* __restrict__ in, float* __restrict__ outT)
{
    __shared__ float tile[32][33];
    const int bx = blockIdx.x * 32, by = blockIdx.y * 32;
    const int tx = threadIdx.x & 31, ty = threadIdx.x >> 5;   // ty 0..7
    #pragma unroll
    for (int r = ty; r < 32; r += 8)
        tile[r][tx] = in[(size_t)(by + r) * HID + bx + tx];
    __syncthreads();
    #pragma unroll
    for (int r = ty; r < 32; r += 8)
        outT[(size_t)(bx + r) * HID + by + tx] = tile[tx][r];
}

__global__ __launch_bounds__(256) void copy_q_kernel(
    const float* __restrict__ q, float* __restrict__ out)
{
    const int idx = blockIdx.x * 256 + threadIdx.x;   // 0 .. BATCH*HID-1
    const int b = idx >> 10;
    const int h = idx & (HID - 1);
    out[(size_t)(b * NX) * HID + h] = q[(size_t)b * HID + h];
}

// ---------------------------------------------------------------------------
// y[b,h] = sum_k x[b,k] * WK[k,h]   fully reduced in one kernel.
// grid (nc=32, bg=8); block 256 = 8 b-locals x 32 n. x rows staged in LDS.
// WK chunk per block: 1024 x 32 n (128 KiB), reused by 8 b -> 32 MiB total.
// ---------------------------------------------------------------------------
__global__ __launch_bounds__(256) void gemv_y_fused(
    const float* __restrict__ WK, const float* __restrict__ out, int t,
    float* __restrict__ y)
{
    __shared__ float xs[8 * HID];    // 32 KiB
    const int nc  = blockIdx.x;      // 0..31
    const int bg  = blockIdx.y;      // 0..7
    const int tid = threadIdx.x;

    for (int i = tid; i < 8 * HID; i += 256) {
        const int bl = i >> 10, h = i & (HID - 1);
        xs[i] = out[((size_t)((bg * 8 + bl) * NX + t - 1)) * HID + h];
    }
    __syncthreads();

    const int n  = nc * 32 + (tid & 31);
    const int bl = tid >> 5;
    const float* __restrict__ xrow = xs + bl * HID;
    const float* __restrict__ wp   = WK + n;
    float acc = 0.f;
    #pragma unroll 8
    for (int j = 0; j < HID; j++)
        acc += xrow[j] * wp[(size_t)j * HID];
    y[(size_t)(bg * 8 + bl) * HID + n] = acc;
}

// ---------------------------------------------------------------------------
// scores[b,s] = sum_h y[b,h] * hidden[s,b,h]     (one wave per hidden row)
// ---------------------------------------------------------------------------
__global__ __launch_bounds__(256) void scores_kernel(
    const float* __restrict__ hidden, const float* __restrict__ y,
    float* __restrict__ scores)
{
    const int gid  = blockIdx.x * 4 + (threadIdx.x >> 6);  // row = s*64 + b
    const int lane = threadIdx.x & 63;
    const int b = gid & (BATCH - 1);
    const int s = gid >> 6;

    const float* hp  = hidden + (size_t)gid * HID + lane * 16;
    const float* ypr = y + (size_t)b * HID + lane * 16;

    float sum = 0.f;
    #pragma unroll
    for (int i = 0; i < 4; i++) {
        float4 hv = *(const float4*)(hp + i * 4);
        float4 yv = *(const float4*)(ypr + i * 4);
        sum += hv.x * yv.x + hv.y * yv.y + hv.z * yv.z + hv.w * yv.w;
    }
    #pragma unroll
    for (int off = 32; off; off >>= 1) sum += __shfl_xor(sum, off);
    if (lane == 0) scores[b * SEQ + s] = sum;
}

// ---------------------------------------------------------------------------
// softmax (redundant per block) + zsum partial over 64 s positions.
// grid (hc=4, sg=8, b=64), block 256.
// zp[b, sg, h] = sum_{s in sg} attn[b,s] * hidden[s,b,h]   (already /sum)
// ---------------------------------------------------------------------------
__global__ __launch_bounds__(256) void softmax_zsum_kernel(
    const float* __restrict__ hidden, const float* __restrict__ scores,
    float* __restrict__ zp)
{
    const int hc  = blockIdx.x;
    const int sg  = blockIdx.y;
    const int b   = blockIdx.z;
    const int tid = threadIdx.x;
    const int w = tid >> 6, lane = tid & 63;

    __shared__ float sc[SEQ];
    __shared__ float red[8];

    float v0 = scores[b * SEQ + tid];
    float v1 = scores[b * SEQ + tid + 256];
    float mx = fmaxf(v0, v1);
    #pragma unroll
    for (int off = 32; off; off >>= 1) mx = fmaxf(mx, __shfl_xor(mx, off));
    if (lane == 0) red[w] = mx;
    __syncthreads();
    mx = fmaxf(fmaxf(red[0], red[1]), fmaxf(red[2], red[3]));

    float e0 = expf(v0 - mx), e1 = expf(v1 - mx);
    sc[tid] = e0; sc[tid + 256] = e1;
    float se = e0 + e1;
    #pragma unroll
    for (int off = 32; off; off >>= 1) se += __shfl_xor(se, off);
    if (lane == 0) red[4 + w] = se;
    __syncthreads();
    const float inv = 1.0f / (red[4] + red[5] + red[6] + red[7]);

    const int h = hc * 256 + tid;
    const float* __restrict__ hp = hidden + ((size_t)(sg * 64) * BATCH + b) * HID + h;
    const float* __restrict__ ap = sc + sg * 64;
    float acc = 0.f;
    #pragma unroll 8
    for (int si = 0; si < 64; si++)
        acc += ap[si] * hp[(size_t)si * BATCH * HID];
    zp[((size_t)(b * 8 + sg)) * HID + h] = acc * inv;
}

// ---------------------------------------------------------------------------
// out[b,t,n] = sum_h z[b,h] * WVT[h,n] + bV[n], z = sum_g zp[b,g,:]
// grid (nc=32, bg=8); block 256 = 8 b-locals x 32 n. z staged in LDS.
// ---------------------------------------------------------------------------
__global__ __launch_bounds__(256) void out_fused_kernel(
    const float* __restrict__ WVT, const float* __restrict__ zp,
    const float* __restrict__ bV, float* __restrict__ out, int t)
{
    __shared__ float zs[8 * HID];    // 32 KiB
    const int nc  = blockIdx.x;      // 0..31
    const int bg  = blockIdx.y;      // 0..7
    const int tid = threadIdx.x;

    for (int i = tid; i < 8 * HID; i += 256) {
        const int bl = i >> 10, h = i & (HID - 1);
        const float* __restrict__ p = zp + ((size_t)((bg * 8 + bl) * 8)) * HID + h;
        float s = 0.f;
        #pragma unroll
        for (int g = 0; g < 8; g++) s += p[(size_t)g * HID];
        zs[i] = s;
    }
    __syncthreads();

    const int n  = nc * 32 + (tid & 31);
    const int bl = tid >> 5;
    const float* __restrict__ zrow = zs + bl * HID;
    const float* __restrict__ wp   = WVT + n;
    float acc = 0.f;
    #pragma unroll 8
    for (int h = 0; h < HID; h++)
        acc += zrow[h] * wp[(size_t)h * HID];
    out[((size_t)((bg * 8 + bl) * NX + t)) * HID + n] = acc + bV[n];
}

// ---------------------------------------------------------------------------
extern "C" void kernel_launch(void* const* d_in, const int* in_sizes, int n_in,
                              void* d_out, int out_size, void* d_ws, size_t ws_size,
                              hipStream_t stream)
{
    const float* hidden = (const float*)d_in[1];
    const float* q      = (const float*)d_in[2];
    const float* WK     = (const float*)d_in[3];
    const float* WV     = (const float*)d_in[5];
    const float* bV     = (const float*)d_in[6];
    float* out = (float*)d_out;

    char* ws = (char*)d_ws;
    float* WVT    = (float*)(ws);                             // 4 MiB
    float* y      = (float*)(ws + (4 << 20));                 // 256 KiB
    float* scores = (float*)(ws + (4 << 20) + (256 << 10));   // 128 KiB
    float* zp     = (float*)(ws + (4 << 20) + (512 << 10));   // 2 MiB

    transpose_k<<<dim3(32, 32), 256, 0, stream>>>(WV, WVT);
    copy_q_kernel<<<(BATCH * HID) / 256, 256, 0, stream>>>(q, out);

    for (int t = 1; t < NX; t++) {
        gemv_y_fused<<<dim3(32, 8), 256, 0, stream>>>(WK, out, t, y);
        scores_kernel<<<(BATCH * SEQ) / 4, 256, 0, stream>>>(hidden, y, scores);
        softmax_zsum_kernel<<<dim3(4, 8, BATCH), 256, 0, stream>>>(hidden, scores, zp);
        out_fused_kernel<<<dim3(32, 8), 256, 0, stream>>>(WVT, zp, bV, out, t);
    }
}

// Round 4
// 536.763 us; speedup vs baseline: 1.9285x; 1.9285x over previous
//
#include <hip/hip_runtime.h>

#define SEQ   512
#define BATCH 64
#define HID   1024
#define NX    8

// ---------------------------------------------------------------------------
// WVT[h][n] = WV[n][h]  (one-time 32x32 tiled transpose)
// ---------------------------------------------------------------------------
__global__ __launch_bounds__(256) void transpose_k(
    const float* __restrict__ in, float* __restrict__ outT)
{
    __shared__ float tile[32][33];
    const int bx = blockIdx.x * 32, by = blockIdx.y * 32;
    const int tx = threadIdx.x & 31, ty = threadIdx.x >> 5;   // ty 0..7
    #pragma unroll
    for (int r = ty; r < 32; r += 8)
        tile[r][tx] = in[(size_t)(by + r) * HID + bx + tx];
    __syncthreads();
    #pragma unroll
    for (int r = ty; r < 32; r += 8)
        outT[(size_t)(bx + r) * HID + by + tx] = tile[tx][r];
}

__global__ __launch_bounds__(256) void copy_q_kernel(
    const float* __restrict__ q, float* __restrict__ out)
{
    const int idx = blockIdx.x * 256 + threadIdx.x;   // 0 .. BATCH*HID-1
    const int b = idx >> 10;
    const int h = idx & (HID - 1);
    out[(size_t)(b * NX) * HID + h] = q[(size_t)b * HID + h];
}

// ---------------------------------------------------------------------------
// yp[b, jg, n] = sum_{j in jg} x[b,j] * WK[j,n]
// grid (nc=4, jg=8, bg=8), block 256. Each block: 256 n x 128 j x 8 b.
// x slice staged in LDS as xs[j][bl]; weight line read once per 8 batches.
// ---------------------------------------------------------------------------
__global__ __launch_bounds__(256) void gemv_y_kernel(
    const float* __restrict__ WK, const float* __restrict__ out, int t,
    float* __restrict__ yp)
{
    __shared__ float xs[128 * 8];      // [j][bl], 4 KiB
    const int nc = blockIdx.x, jg = blockIdx.y, bg = blockIdx.z;
    const int tid = threadIdx.x;

    for (int i = tid; i < 128 * 8; i += 256) {
        const int j = i >> 3, bl = i & 7;
        xs[i] = out[((size_t)((bg * 8 + bl) * NX + t - 1)) * HID + jg * 128 + j];
    }
    __syncthreads();

    const int n = nc * 256 + tid;
    const float* __restrict__ wp = WK + (size_t)(jg * 128) * HID + n;
    float acc[8] = {};
    #pragma unroll 4
    for (int j = 0; j < 128; j++) {
        const float w = wp[(size_t)j * HID];
        const float4 x0 = *(const float4*)(xs + j * 8 + 0);
        const float4 x1 = *(const float4*)(xs + j * 8 + 4);
        acc[0] += w * x0.x; acc[1] += w * x0.y;
        acc[2] += w * x0.z; acc[3] += w * x0.w;
        acc[4] += w * x1.x; acc[5] += w * x1.y;
        acc[6] += w * x1.z; acc[7] += w * x1.w;
    }
    #pragma unroll
    for (int bl = 0; bl < 8; bl++)
        yp[((size_t)((bg * 8 + bl) * 8 + jg)) * HID + n] = acc[bl];
}

// yp [64][8][1024] -> y [64][1024]
__global__ __launch_bounds__(256) void reduce8_kernel(
    const float* __restrict__ part, float* __restrict__ full)
{
    const int idx = blockIdx.x * 256 + threadIdx.x;
    const int b = idx >> 10, h = idx & (HID - 1);
    float s = 0.f;
    #pragma unroll
    for (int g = 0; g < 8; g++) s += part[((size_t)b * 8 + g) * HID + h];
    full[idx] = s;
}

// ---------------------------------------------------------------------------
// scores[b,s] = sum_h y[b,h] * hidden[s,b,h]     (one wave per hidden row)
// ---------------------------------------------------------------------------
__global__ __launch_bounds__(256) void scores_kernel(
    const float* __restrict__ hidden, const float* __restrict__ y,
    float* __restrict__ scores)
{
    const int gid  = blockIdx.x * 4 + (threadIdx.x >> 6);  // row = s*64 + b
    const int lane = threadIdx.x & 63;
    const int b = gid & (BATCH - 1);
    const int s = gid >> 6;

    const float* hp  = hidden + (size_t)gid * HID + lane * 16;
    const float* ypr = y + (size_t)b * HID + lane * 16;

    float sum = 0.f;
    #pragma unroll
    for (int i = 0; i < 4; i++) {
        float4 hv = *(const float4*)(hp + i * 4);
        float4 yv = *(const float4*)(ypr + i * 4);
        sum += hv.x * yv.x + hv.y * yv.y + hv.z * yv.z + hv.w * yv.w;
    }
    #pragma unroll
    for (int off = 32; off; off >>= 1) sum += __shfl_xor(sum, off);
    if (lane == 0) scores[b * SEQ + s] = sum;
}

// ---------------------------------------------------------------------------
// softmax (redundant per block) + zsum partial over 64 s positions.
// grid (hc=4, sg=8, b=64), block 256.
// zp[b, sg, h] = sum_{s in sg} attn[b,s] * hidden[s,b,h]   (already /sum)
// ---------------------------------------------------------------------------
__global__ __launch_bounds__(256) void softmax_zsum_kernel(
    const float* __restrict__ hidden, const float* __restrict__ scores,
    float* __restrict__ zp)
{
    const int hc  = blockIdx.x;
    const int sg  = blockIdx.y;
    const int b   = blockIdx.z;
    const int tid = threadIdx.x;
    const int w = tid >> 6, lane = tid & 63;

    __shared__ float sc[SEQ];
    __shared__ float red[8];

    float v0 = scores[b * SEQ + tid];
    float v1 = scores[b * SEQ + tid + 256];
    float mx = fmaxf(v0, v1);
    #pragma unroll
    for (int off = 32; off; off >>= 1) mx = fmaxf(mx, __shfl_xor(mx, off));
    if (lane == 0) red[w] = mx;
    __syncthreads();
    mx = fmaxf(fmaxf(red[0], red[1]), fmaxf(red[2], red[3]));

    float e0 = expf(v0 - mx), e1 = expf(v1 - mx);
    sc[tid] = e0; sc[tid + 256] = e1;
    float se = e0 + e1;
    #pragma unroll
    for (int off = 32; off; off >>= 1) se += __shfl_xor(se, off);
    if (lane == 0) red[4 + w] = se;
    __syncthreads();
    const float inv = 1.0f / (red[4] + red[5] + red[6] + red[7]);

    const int h = hc * 256 + tid;
    const float* __restrict__ hp = hidden + ((size_t)(sg * 64) * BATCH + b) * HID + h;
    const float* __restrict__ ap = sc + sg * 64;
    float acc = 0.f;
    #pragma unroll 8
    for (int si = 0; si < 64; si++)
        acc += ap[si] * hp[(size_t)si * BATCH * HID];
    zp[((size_t)(b * 8 + sg)) * HID + h] = acc * inv;
}

// ---------------------------------------------------------------------------
// op[b, hg, n] = sum_{h in hg} z[b,h] * WVT[h,n], z = sum_g zp[b,g,:]
// grid (nc=4, hg=8, bg=8), block 256. z slice reduced into LDS during staging.
// ---------------------------------------------------------------------------
__global__ __launch_bounds__(256) void gemv_out_kernel(
    const float* __restrict__ WVT, const float* __restrict__ zp,
    float* __restrict__ op)
{
    __shared__ float zs[128 * 8];      // [h][bl], 4 KiB
    const int nc = blockIdx.x, hg = blockIdx.y, bg = blockIdx.z;
    const int tid = threadIdx.x;

    for (int i = tid; i < 128 * 8; i += 256) {
        const int h = i >> 3, bl = i & 7;
        const float* __restrict__ p =
            zp + ((size_t)((bg * 8 + bl) * 8)) * HID + hg * 128 + h;
        float s = 0.f;
        #pragma unroll
        for (int g = 0; g < 8; g++) s += p[(size_t)g * HID];
        zs[i] = s;
    }
    __syncthreads();

    const int n = nc * 256 + tid;
    const float* __restrict__ wp = WVT + (size_t)(hg * 128) * HID + n;
    float acc[8] = {};
    #pragma unroll 4
    for (int h = 0; h < 128; h++) {
        const float w = wp[(size_t)h * HID];
        const float4 z0 = *(const float4*)(zs + h * 8 + 0);
        const float4 z1 = *(const float4*)(zs + h * 8 + 4);
        acc[0] += w * z0.x; acc[1] += w * z0.y;
        acc[2] += w * z0.z; acc[3] += w * z0.w;
        acc[4] += w * z1.x; acc[5] += w * z1.y;
        acc[6] += w * z1.z; acc[7] += w * z1.w;
    }
    #pragma unroll
    for (int bl = 0; bl < 8; bl++)
        op[((size_t)((bg * 8 + bl) * 8 + hg)) * HID + n] = acc[bl];
}

// op [64][8][1024] + bias -> out[(b*NX+t)*HID + n]
__global__ __launch_bounds__(256) void reduce8_bias_kernel(
    const float* __restrict__ part, const float* __restrict__ bias,
    float* __restrict__ out, int t)
{
    const int idx = blockIdx.x * 256 + threadIdx.x;
    const int b = idx >> 10, n = idx & (HID - 1);
    float s = bias[n];
    #pragma unroll
    for (int g = 0; g < 8; g++) s += part[((size_t)b * 8 + g) * HID + n];
    out[((size_t)b * NX + t) * HID + n] = s;
}

// ---------------------------------------------------------------------------
extern "C" void kernel_launch(void* const* d_in, const int* in_sizes, int n_in,
                              void* d_out, int out_size, void* d_ws, size_t ws_size,
                              hipStream_t stream)
{
    const float* hidden = (const float*)d_in[1];
    const float* q      = (const float*)d_in[2];
    const float* WK     = (const float*)d_in[3];
    const float* WV     = (const float*)d_in[5];
    const float* bV     = (const float*)d_in[6];
    float* out = (float*)d_out;

    char* ws = (char*)d_ws;
    float* WVT    = (float*)(ws);                             // 4 MiB
    float* y      = (float*)(ws + (4 << 20));                 // 256 KiB
    float* scores = (float*)(ws + (4 << 20) + (256 << 10));   // 128 KiB
    float* yp     = (float*)(ws + (5 << 20));                 // 2 MiB
    float* zp     = (float*)(ws + (7 << 20));                 // 2 MiB
    float* op     = (float*)(ws + (9 << 20));                 // 2 MiB

    transpose_k<<<dim3(32, 32), 256, 0, stream>>>(WV, WVT);
    copy_q_kernel<<<(BATCH * HID) / 256, 256, 0, stream>>>(q, out);

    for (int t = 1; t < NX; t++) {
        gemv_y_kernel<<<dim3(4, 8, 8), 256, 0, stream>>>(WK, out, t, yp);
        reduce8_kernel<<<(BATCH * HID) / 256, 256, 0, stream>>>(yp, y);
        scores_kernel<<<(BATCH * SEQ) / 4, 256, 0, stream>>>(hidden, y, scores);
        softmax_zsum_kernel<<<dim3(4, 8, BATCH), 256, 0, stream>>>(hidden, scores, zp);
        gemv_out_kernel<<<dim3(4, 8, 8), 256, 0, stream>>>(WVT, zp, op);
        reduce8_bias_kernel<<<(BATCH * HID) / 256, 256, 0, stream>>>(op, bV, out, t);
    }
}

// Round 5
// 508.382 us; speedup vs baseline: 2.0362x; 1.0558x over previous
//
#include <hip/hip_runtime.h>

#define SEQ   512
#define BATCH 64
#define HID   1024
#define NX    8
#define SG    16          // s-groups per batch in fused attention
#define SROWS (SEQ / SG)  // 32 rows per group

// ---------------------------------------------------------------------------
// WVT[h][n] = WV[n][h]  (one-time 32x32 tiled transpose)
// ---------------------------------------------------------------------------
__global__ __launch_bounds__(256) void transpose_k(
    const float* __restrict__ in, float* __restrict__ outT)
{
    __shared__ float tile[32][33];
    const int bx = blockIdx.x * 32, by = blockIdx.y * 32;
    const int tx = threadIdx.x & 31, ty = threadIdx.x >> 5;
    #pragma unroll
    for (int r = ty; r < 32; r += 8)
        tile[r][tx] = in[(size_t)(by + r) * HID + bx + tx];
    __syncthreads();
    #pragma unroll
    for (int r = ty; r < 32; r += 8)
        outT[(size_t)(bx + r) * HID + by + tx] = tile[tx][r];
}

// ---------------------------------------------------------------------------
// gemv_y: yp[b, jg, n] = sum_{j in jg} x[b,j] * WK[j,n]
// grid (nc=4, jg=8, b=64) = 2048 blocks (round-2 proven shape).
// Staging computes x[b, j-slice] from previous step's op partials + bias
// (or q at t==1) and nc==0 also writes it to out row t-1.
// ---------------------------------------------------------------------------
__global__ __launch_bounds__(256) void gemv_y_kernel(
    const float* __restrict__ WK, const float* __restrict__ q,
    const float* __restrict__ op, const float* __restrict__ bV,
    float* __restrict__ out, int t, float* __restrict__ yp)
{
    __shared__ float xs[128];
    const int nc = blockIdx.x, jg = blockIdx.y, b = blockIdx.z;
    const int tid = threadIdx.x;

    if (tid < 128) {
        const int j = jg * 128 + tid;
        float v;
        if (t == 1) {
            v = q[(size_t)b * HID + j];
        } else {
            v = bV[j];
            const float* __restrict__ p = op + (size_t)(b * 8) * HID + j;
            #pragma unroll
            for (int g = 0; g < 8; g++) v += p[(size_t)g * HID];
        }
        xs[tid] = v;
        if (nc == 0) out[((size_t)(b * NX + t - 1)) * HID + j] = v;
    }
    __syncthreads();

    const int n = nc * 256 + tid;
    const float* __restrict__ wp = WK + (size_t)(jg * 128) * HID + n;
    float acc = 0.f;
    #pragma unroll 8
    for (int j = 0; j < 128; j++)
        acc += xs[j] * wp[(size_t)j * HID];
    yp[((size_t)(b * 8 + jg)) * HID + n] = acc;
}

// ---------------------------------------------------------------------------
// fused_attn: per (sg, b) block:
//   1. ys = sum_g yp[b,g,:]                (y reduce folded into staging)
//   2. sc[r] = ys . hidden[sg*32+r, b, :]  (scores, 8 rows per wave)
//   3. local softmax: m = max sc, we = exp(sc-m), l = sum we
//   4. zp[b,sg,h] = sum_r we[r] * hidden[sg*32+r, b, h]   (unnormalized)
// hidden is read once from L3 (scores) and re-read L2-hot (zsum).
// ---------------------------------------------------------------------------
__global__ __launch_bounds__(256) void fused_attn_kernel(
    const float* __restrict__ hidden, const float* __restrict__ yp,
    float* __restrict__ zp, float* __restrict__ ml)
{
    const int sg = blockIdx.x;   // 0..15
    const int b  = blockIdx.y;   // 0..63
    const int tid = threadIdx.x;
    const int w = tid >> 6, lane = tid & 63;

    __shared__ float ys[HID];
    __shared__ float sc[SROWS];
    __shared__ float we[SROWS];

    for (int i = tid; i < HID; i += 256) {
        const float* __restrict__ p = yp + (size_t)(b * 8) * HID + i;
        float s = 0.f;
        #pragma unroll
        for (int g = 0; g < 8; g++) s += p[(size_t)g * HID];
        ys[i] = s;
    }
    __syncthreads();

    // scores: rows w*8 .. w*8+7 of this s-group
    #pragma unroll 2
    for (int ri = 0; ri < 8; ri++) {
        const int r = w * 8 + ri;
        const int s = sg * SROWS + r;
        const float* __restrict__ hp = hidden + ((size_t)s * BATCH + b) * HID + lane * 16;
        const float* __restrict__ yr = ys + lane * 16;
        float sum = 0.f;
        #pragma unroll
        for (int i = 0; i < 4; i++) {
            float4 hv = *(const float4*)(hp + i * 4);
            float4 yv = *(const float4*)(yr + i * 4);
            sum += hv.x * yv.x + hv.y * yv.y + hv.z * yv.z + hv.w * yv.w;
        }
        #pragma unroll
        for (int off = 32; off; off >>= 1) sum += __shfl_xor(sum, off);
        if (lane == 0) sc[r] = sum;
    }
    __syncthreads();

    float m = -1e30f;
    #pragma unroll
    for (int i = 0; i < SROWS; i++) m = fmaxf(m, sc[i]);
    if (tid < SROWS) we[tid] = expf(sc[tid] - m);
    __syncthreads();
    float l = 0.f;
    #pragma unroll
    for (int i = 0; i < SROWS; i++) l += we[i];

    // zsum: thread owns h = tid*4 .. tid*4+3
    float4 acc = {0.f, 0.f, 0.f, 0.f};
    const float* __restrict__ hp2 =
        hidden + ((size_t)(sg * SROWS) * BATCH + b) * HID + tid * 4;
    #pragma unroll 4
    for (int si = 0; si < SROWS; si++) {
        const float wv = we[si];
        float4 hv = *(const float4*)(hp2 + (size_t)si * BATCH * HID);
        acc.x += wv * hv.x; acc.y += wv * hv.y;
        acc.z += wv * hv.z; acc.w += wv * hv.w;
    }
    *(float4*)(zp + ((size_t)(b * SG + sg)) * HID + tid * 4) = acc;
    if (tid == 0) {
        ml[(b * SG + sg) * 2 + 0] = m;
        ml[(b * SG + sg) * 2 + 1] = l;
    }
}

// ---------------------------------------------------------------------------
// gemv_out: op[b, hg, n] = sum_{h in hg} z[b,h] * WVT[h,n]
// grid (nc=4, hg=8, b=64) = 2048 blocks.
// Staging applies the global-softmax rescale:
//   M = max_g m_g ; L = sum_g l_g e^{m_g-M} ; z[h] = sum_g zp[b,g,h] e^{m_g-M} / L
// ---------------------------------------------------------------------------
__global__ __launch_bounds__(256) void gemv_out_kernel(
    const float* __restrict__ WVT, const float* __restrict__ zp,
    const float* __restrict__ ml, float* __restrict__ op)
{
    __shared__ float zs[128];
    const int nc = blockIdx.x, hg = blockIdx.y, b = blockIdx.z;
    const int tid = threadIdx.x;

    float M = -1e30f;
    #pragma unroll
    for (int g = 0; g < SG; g++) M = fmaxf(M, ml[(b * SG + g) * 2]);
    float L = 0.f;
    #pragma unroll
    for (int g = 0; g < SG; g++)
        L += ml[(b * SG + g) * 2 + 1] * expf(ml[(b * SG + g) * 2] - M);
    const float invL = 1.0f / L;

    if (tid < 128) {
        const int h = hg * 128 + tid;
        float s = 0.f;
        #pragma unroll
        for (int g = 0; g < SG; g++)
            s += zp[((size_t)(b * SG + g)) * HID + h] * expf(ml[(b * SG + g) * 2] - M);
        zs[tid] = s * invL;
    }
    __syncthreads();

    const int n = nc * 256 + tid;
    const float* __restrict__ wp = WVT + (size_t)(hg * 128) * HID + n;
    float acc = 0.f;
    #pragma unroll 8
    for (int h = 0; h < 128; h++)
        acc += zs[h] * wp[(size_t)h * HID];
    op[((size_t)(b * 8 + hg)) * HID + n] = acc;
}

// final output row t=NX-1: out = sum_g op + bias
__global__ __launch_bounds__(256) void reduce8_bias_kernel(
    const float* __restrict__ part, const float* __restrict__ bias,
    float* __restrict__ out, int t)
{
    const int idx = blockIdx.x * 256 + threadIdx.x;
    const int b = idx >> 10, n = idx & (HID - 1);
    float s = bias[n];
    #pragma unroll
    for (int g = 0; g < 8; g++) s += part[((size_t)b * 8 + g) * HID + n];
    out[((size_t)b * NX + t) * HID + n] = s;
}

// ---------------------------------------------------------------------------
extern "C" void kernel_launch(void* const* d_in, const int* in_sizes, int n_in,
                              void* d_out, int out_size, void* d_ws, size_t ws_size,
                              hipStream_t stream)
{
    const float* hidden = (const float*)d_in[1];
    const float* q      = (const float*)d_in[2];
    const float* WK     = (const float*)d_in[3];
    const float* WV     = (const float*)d_in[5];
    const float* bV     = (const float*)d_in[6];
    float* out = (float*)d_out;

    char* ws = (char*)d_ws;
    float* WVT = (float*)(ws);                    // 4 MiB
    float* yp  = (float*)(ws + (4  << 20));       // 2 MiB
    float* zp  = (float*)(ws + (6  << 20));       // 4 MiB
    float* ml  = (float*)(ws + (10 << 20));       // 8 KiB
    float* op  = (float*)(ws + (11 << 20));       // 2 MiB

    transpose_k<<<dim3(32, 32), 256, 0, stream>>>(WV, WVT);

    for (int t = 1; t < NX; t++) {
        gemv_y_kernel<<<dim3(4, 8, BATCH), 256, 0, stream>>>(
            WK, q, op, bV, out, t, yp);
        fused_attn_kernel<<<dim3(SG, BATCH), 256, 0, stream>>>(
            hidden, yp, zp, ml);
        gemv_out_kernel<<<dim3(4, 8, BATCH), 256, 0, stream>>>(
            WVT, zp, ml, op);
    }
    reduce8_bias_kernel<<<(BATCH * HID) / 256, 256, 0, stream>>>(
        op, bV, out, NX - 1);
}